// Round 19
// baseline (1138.382 us; speedup 1.0000x reference)
//
#include <hip/hip_runtime.h>
#include <stdint.h>

#define B_ 4
#define H_ 16
#define S_ 2048
#define D_ 64
#define NWIN 64                       /* 32-k windows, full S */
#define EBS 40                       /* ebounce row stride (shorts) */
#define VBS 40                       /* vbuf row stride (shorts) */
#define MSTR 17                      /* mask-chunk row stride (words) */

typedef __attribute__((ext_vector_type(8))) short short8;
typedef __attribute__((ext_vector_type(4))) float float4v;
typedef __attribute__((ext_vector_type(4))) unsigned int uint4v;
typedef __attribute__((ext_vector_type(2))) unsigned int uint2v;

static __device__ __forceinline__ short f2bf(float f) {
  uint32_t u = __builtin_bit_cast(uint32_t, f);
  u = (u + 0x7FFFu + ((u >> 16) & 1u)) >> 16;   // RNE
  return (short)u;
}
static __device__ __forceinline__ float bf2f(uint32_t s) {
  return __builtin_bit_cast(float, s << 16);
}
static __device__ __forceinline__ uint32_t cvtpk(float lo, float hi) {
  uint32_t r;
  asm("v_cvt_pk_bf16_f32 %0, %1, %2" : "=v"(r) : "v"(lo), "v"(hi));
  return r;
}
static __device__ __forceinline__ uint32_t nz4(uint32_t d) {
  uint32_t x = (d & 0x7F7F7F7Fu) + 0x7F7F7F7Fu;
  x = (x | d) & 0x80808080u;
  return x >> 7;
}
static __device__ __forceinline__ uint32_t nib(uint32_t d) {
  return ((nz4(d) * 0x01020408u) >> 24) & 0xFu;
}

// workspace layout
#define LINV_OFF   ((size_t)64)
#define LINV_BYTES ((size_t)B_ * H_ * S_ * 4)
#define KBF_OFF    (LINV_OFF + LINV_BYTES)
#define KBF_BYTES  ((size_t)B_ * H_ * S_ * D_ * 2)
#define VT_OFF     (KBF_OFF + KBF_BYTES)
#define VT_BYTES   ((size_t)B_ * H_ * S_ * D_ * 2)
#define MB_OFF     (VT_OFF + VT_BYTES)
#define MB_BYTES   ((size_t)B_ * H_ * S_ * 64 * 4)   /* [bh][4][S][16w] */

__global__ void detect_mask_dtype(const uint8_t* __restrict__ m, uint32_t* flag) {
  uint32_t a = 0, b = 0;
  for (int i = threadIdx.x; i < 65536; i += 256) {
    uint8_t x = m[i];
    if (i & 3) a |= x; else b |= x;
  }
  uint32_t bits = (a ? 1u : 0u) | (b ? 2u : 0u);
  if (bits) atomicOr(flag, bits);
}

__global__ __launch_bounds__(256) void prep_k(const float* __restrict__ K,
                                              short* __restrict__ Kbf) {
  size_t base = ((size_t)blockIdx.x * 256 + threadIdx.x) * 8;
  float4v a = *(const float4v*)(K + base);
  float4v b = *(const float4v*)(K + base + 4);
  short8 o;
  o[0]=f2bf(a.x); o[1]=f2bf(a.y); o[2]=f2bf(a.z); o[3]=f2bf(a.w);
  o[4]=f2bf(b.x); o[5]=f2bf(b.y); o[6]=f2bf(b.z); o[7]=f2bf(b.w);
  *(short8*)(Kbf + base) = o;
}

__global__ __launch_bounds__(256) void prep_vt(const float* __restrict__ V,
                                               short* __restrict__ VT) {
  __shared__ short tile[64][72];
  int bh = blockIdx.x >> 5, k0 = (blockIdx.x & 31) * 64;
  const float* src = V + ((size_t)bh * S_ + k0) * D_;
  int t = threadIdx.x;
  int r = t >> 2, c0 = (t & 3) * 16;
#pragma unroll
  for (int j = 0; j < 4; ++j) {
    float4v f = *(const float4v*)(src + (size_t)r * D_ + c0 + j * 4);
    tile[r][c0 + j*4 + 0] = f2bf(f.x);
    tile[r][c0 + j*4 + 1] = f2bf(f.y);
    tile[r][c0 + j*4 + 2] = f2bf(f.z);
    tile[r][c0 + j*4 + 3] = f2bf(f.w);
  }
  __syncthreads();
  int d = t >> 2, ks0 = (t & 3) * 16;
  short* dst = VT + (size_t)bh * D_ * S_ + (size_t)d * S_ + k0 + ks0;
#pragma unroll
  for (int half = 0; half < 2; ++half) {
    short8 o;
#pragma unroll
    for (int i = 0; i < 8; ++i) o[i] = tile[ks0 + half * 8 + i][d];
    *(short8*)(dst + half * 8) = o;
  }
}

// === Pass 1: rowsums + PV + context; K,V LDS-relayed; mask bitmap STREAMED ===
template <int PREP, int BM>
__global__ __launch_bounds__(512, 6) void k_sums(
    const float* __restrict__ Q, const float* __restrict__ K,
    const float* __restrict__ V, const float* __restrict__ scale_p,
    const uint8_t* __restrict__ M, const uint32_t* __restrict__ flag,
    const short* __restrict__ Kbf, const short* __restrict__ VT,
    float* __restrict__ linvG, uint32_t* __restrict__ mbitsG,
    float* __restrict__ outC)
{
  __shared__ char smemraw[46080];               // 45 KB -> 3 blocks/CU
  uint32_t* mstrA = (uint32_t*)smemraw;         // [2][128][MSTR]  17408 B
  short*    kbufA = (short*)(smemraw + 17408);  // [2][32*64]       8192 B
  short*    vbufA = (short*)(smemraw + 25600);  // [2][64*VBS]     10240 B
  short*    ebA   = (short*)(smemraw + 35840);  // [8][16*EBS]     10240 B

  const int bx  = (blockIdx.x & 7) * 128 + (blockIdx.x >> 3);
  const int bh  = bx >> 4;
  const int q0  = (bx & 15) * 128;

  const int tid  = threadIdx.x;
  const int widx = tid >> 6;
  const int lane = tid & 63;
  const int g    = lane >> 4;
  const int c    = lane & 15;
  const int qrow = q0 + widx * 16 + c;

  const float scale = scale_p[0];
  const uint32_t fl = flag[0];

  const short* Kbp = Kbf + (size_t)bh * S_ * D_;
  const short* VTp = VT + (size_t)bh * D_ * S_;
  const float* Kfp = K + (size_t)bh * S_ * D_;
  const float* Vfp = V + (size_t)bh * S_ * D_;

  // BUILDHALF(CC,HF): build words (t&3)*4 + HF*2 .. +1 of chunk CC into buffer CC&1,
  // and (BM) plain-store them to the ws bitmap (chunk-major layout).
  const int brow_ = tid >> 2;
  const int bwb0_ = (tid & 3) * 4;
#define BUILDHALF(CC, HF) do {                                                 \
    const int wb_ = bwb0_ + (HF) * 2;                                          \
    uint32_t w0_, w1_;                                                         \
    if (fl == 3u) {                                                            \
      const uint8_t* mp_ = M + ((size_t)(bh * S_ + q0 + brow_)) * S_           \
                             + (CC) * 512 + wb_ * 32;                          \
      uint4v a0_ = *(const uint4v*)mp_;                                        \
      uint4v b0_ = *(const uint4v*)(mp_ + 16);                                 \
      uint4v a1_ = *(const uint4v*)(mp_ + 32);                                 \
      uint4v b1_ = *(const uint4v*)(mp_ + 48);                                 \
      w0_ = nib(a0_.x) | (nib(a0_.y) << 4) | (nib(a0_.z) << 8)  | (nib(a0_.w) << 12) \
          | (nib(b0_.x) << 16) | (nib(b0_.y) << 20) | (nib(b0_.z) << 24) | (nib(b0_.w) << 28); \
      w1_ = nib(a1_.x) | (nib(a1_.y) << 4) | (nib(a1_.z) << 8)  | (nib(a1_.w) << 12) \
          | (nib(b1_.x) << 16) | (nib(b1_.y) << 20) | (nib(b1_.z) << 24) | (nib(b1_.w) << 28); \
    } else {                                                                   \
      const uint32_t* mp_ = (const uint32_t*)M                                 \
          + ((size_t)(bh * S_ + q0 + brow_)) * S_ + (CC) * 512 + wb_ * 32;     \
      w0_ = 0; w1_ = 0;                                                        \
      for (int u_ = 0; u_ < 8; ++u_) {                                         \
        uint4v v_ = *(const uint4v*)(mp_ + u_ * 4);                            \
        uint32_t nz_ = (v_.x ? 1u : 0u) | (v_.y ? 2u : 0u) | (v_.z ? 4u : 0u) | (v_.w ? 8u : 0u); \
        w0_ |= nz_ << (u_ * 4);                                                \
      }                                                                        \
      for (int u_ = 0; u_ < 8; ++u_) {                                         \
        uint4v v_ = *(const uint4v*)(mp_ + 32 + u_ * 4);                       \
        uint32_t nz_ = (v_.x ? 1u : 0u) | (v_.y ? 2u : 0u) | (v_.z ? 4u : 0u) | (v_.w ? 8u : 0u); \
        w1_ |= nz_ << (u_ * 4);                                                \
      }                                                                        \
    }                                                                          \
    uint32_t* md_ = mstrA + ((CC) & 1) * 128 * MSTR + brow_ * MSTR + wb_;      \
    md_[0] = w0_; md_[1] = w1_;                                                \
    if (BM) {                                                                  \
      uint32_t* mg_ = mbitsG + ((size_t)(bh * 4 + (CC)) * S_ + q0 + brow_) * 16 + wb_; \
      mg_[0] = w0_; mg_[1] = w1_;                                              \
    } } while (0)

  // ---- Q as B-frag: lane holds Q[qrow][.] ----
  short8 qB[2];
  {
    const float* qr = Q + ((size_t)(bh * S_ + qrow)) * D_;
    float4v x0 = *(const float4v*)(qr + g * 8);
    float4v x1 = *(const float4v*)(qr + g * 8 + 4);
    float4v y0 = *(const float4v*)(qr + 32 + g * 8);
    float4v y1 = *(const float4v*)(qr + 32 + g * 8 + 4);
    short8 f;
    f[0]=f2bf(x0.x); f[1]=f2bf(x0.y); f[2]=f2bf(x0.z); f[3]=f2bf(x0.w);
    f[4]=f2bf(x1.x); f[5]=f2bf(x1.y); f[6]=f2bf(x1.z); f[7]=f2bf(x1.w);
    qB[0] = f;
    f[0]=f2bf(y0.x); f[1]=f2bf(y0.y); f[2]=f2bf(y0.z); f[3]=f2bf(y0.w);
    f[4]=f2bf(y1.x); f[5]=f2bf(y1.y); f[6]=f2bf(y1.z); f[7]=f2bf(y1.w);
    qB[1] = f;
  }

  // ---- staging: waves 0-3 relay K (XOR-swizzled), waves 4-7 relay V ----
  const bool kstager = (widx < 4);
  const bool vstager = (widx >= 4) && (PREP != 0);
  const int  sr = (widx << 3) + (lane >> 3);
  const int  sp = lane & 7;
  const int  sdst = sr * 64 + ((sp ^ (sr & 7)) << 3);
  const int  vr = ((widx - 4) << 4) + (lane >> 2);
  const int  vp = lane & 3;
  short8  kreg, vreg;
  float4v kf0, kf1;
#define ISSUE(W) do {                                                          \
    if (kstager) {                                                             \
      if (PREP) kreg = *(const short8*)(Kbp + (size_t)((W) * 32 + sr) * 64 + sp * 8); \
      else { const float* s_ = Kfp + (size_t)((W) * 32 + sr) * 64 + sp * 8;    \
             kf0 = *(const float4v*)s_; kf1 = *(const float4v*)(s_ + 4); }     \
    } else if (vstager) {                                                      \
      vreg = *(const short8*)(VTp + (size_t)vr * S_ + (W) * 32 + vp * 8);      \
    } } while (0)
#define WRITE(BUF) do {                                                        \
    if (kstager) {                                                             \
      short8 o_;                                                               \
      if (PREP) o_ = kreg;                                                     \
      else { o_[0]=f2bf(kf0.x); o_[1]=f2bf(kf0.y); o_[2]=f2bf(kf0.z); o_[3]=f2bf(kf0.w); \
             o_[4]=f2bf(kf1.x); o_[5]=f2bf(kf1.y); o_[6]=f2bf(kf1.z); o_[7]=f2bf(kf1.w); } \
      *(short8*)&kbufA[(BUF) * 2048 + sdst] = o_;                              \
    } else if (vstager) {                                                      \
      *(short8*)&vbufA[(BUF) * 64 * VBS + vr * VBS + vp * 8] = vreg;           \
    } } while (0)

  const int ka0 = ((g       ^ (c & 7)) << 3);
  const int ka1 = (((g + 4) ^ (c & 7)) << 3);

  // prologue: mask chunk 0, first K/V windows
  BUILDHALF(0, 0);
  BUILDHALF(0, 1);
  ISSUE(0); WRITE(0); ISSUE(1);
  __syncthreads();

  float rsv = 0.0f;
  float4v cacc[4];
#pragma unroll
  for (int nd = 0; nd < 4; ++nd) cacc[nd] = (float4v){0.f, 0.f, 0.f, 0.f};
  short* eb = ebA + widx * 16 * EBS;

#pragma unroll 1
  for (int chunk = 0; chunk < 4; ++chunk) {
    const uint32_t* mrowc = mstrA + (chunk & 1) * 128 * MSTR + (widx * 16 + c) * MSTR;
#pragma unroll 1
    for (int w16 = 0; w16 < 16; ++w16) {
      const int w = chunk * 16 + w16;
      const int cur = w & 1;
      const int kwin = w * 32;

      short8 vA0, vA1, vA2, vA3;
      if (PREP) {
        const short* vb = vbufA + cur * 64 * VBS;
        vA0 = *(const short8*)(vb + (size_t)(c)      * VBS + g * 8);
        vA1 = *(const short8*)(vb + (size_t)(16 + c) * VBS + g * 8);
        vA2 = *(const short8*)(vb + (size_t)(32 + c) * VBS + g * 8);
        vA3 = *(const short8*)(vb + (size_t)(48 + c) * VBS + g * 8);
      } else {
        const float* vc = Vfp + (size_t)(kwin + g * 8) * D_ + c;
#pragma unroll
        for (int e = 0; e < 8; ++e) {
          vA0[e] = f2bf(vc[(size_t)e * D_]);
          vA1[e] = f2bf(vc[(size_t)e * D_ + 16]);
          vA2[e] = f2bf(vc[(size_t)e * D_ + 32]);
          vA3[e] = f2bf(vc[(size_t)e * D_ + 48]);
        }
      }

      const short* kb = kbufA + cur * 2048;
      short8 a0 = *(const short8*)(kb + c * 64 + ka0);
      short8 a1 = *(const short8*)(kb + c * 64 + ka1);
      short8 a2 = *(const short8*)(kb + (c + 16) * 64 + ka0);
      short8 a3 = *(const short8*)(kb + (c + 16) * 64 + ka1);

      float4v acc0 = (float4v){0.f,0.f,0.f,0.f};
      float4v acc1 = (float4v){0.f,0.f,0.f,0.f};
      acc0 = __builtin_amdgcn_mfma_f32_16x16x32_bf16(a0, qB[0], acc0, 0, 0, 0);
      acc0 = __builtin_amdgcn_mfma_f32_16x16x32_bf16(a1, qB[1], acc0, 0, 0, 0);
      acc1 = __builtin_amdgcn_mfma_f32_16x16x32_bf16(a2, qB[0], acc1, 0, 0, 0);
      acc1 = __builtin_amdgcn_mfma_f32_16x16x32_bf16(a3, qB[1], acc1, 0, 0, 0);

      const uint32_t mw = mrowc[w16];
      float e0[4], e1[4];
#pragma unroll
      for (int r = 0; r < 4; ++r) {
        e0[r] = ((mw >> (4 * g + r)) & 1u)      ? 1.0f : __expf(acc0[r] * scale);
        e1[r] = ((mw >> (16 + 4 * g + r)) & 1u) ? 1.0f : __expf(acc1[r] * scale);
        rsv += e0[r] + e1[r];
      }
      uint2v lo, hi2;
      lo.x  = cvtpk(e0[0], e0[1]);  lo.y  = cvtpk(e0[2], e0[3]);
      hi2.x = cvtpk(e1[0], e1[1]);  hi2.y = cvtpk(e1[2], e1[3]);
      *(uint2v*)&eb[c * EBS + 4 * g]      = lo;
      *(uint2v*)&eb[c * EBS + 16 + 4 * g] = hi2;
      const short8 bfrag = *(const short8*)&eb[c * EBS + g * 8];

      cacc[0] = __builtin_amdgcn_mfma_f32_16x16x32_bf16(vA0, bfrag, cacc[0], 0, 0, 0);
      cacc[1] = __builtin_amdgcn_mfma_f32_16x16x32_bf16(vA1, bfrag, cacc[1], 0, 0, 0);
      cacc[2] = __builtin_amdgcn_mfma_f32_16x16x32_bf16(vA2, bfrag, cacc[2], 0, 0, 0);
      cacc[3] = __builtin_amdgcn_mfma_f32_16x16x32_bf16(vA3, bfrag, cacc[3], 0, 0, 0);

      // streamed mask: build next chunk (other buffer) mid-chunk
      if (chunk < 3 && w16 == 4) BUILDHALF(chunk + 1, 0);
      if (chunk < 3 && w16 == 8) BUILDHALF(chunk + 1, 1);

      if (w + 1 < NWIN) {
        WRITE(cur ^ 1);
        if (w + 2 < NWIN) ISSUE(w + 2);
        __syncthreads();
      }
    }
  }
#undef ISSUE
#undef WRITE
#undef BUILDHALF

  rsv += __shfl_xor(rsv, 16);
  rsv += __shfl_xor(rsv, 32);
  const float linv = 1.0f / rsv;
  if (g == 0) linvG[(size_t)bh * S_ + qrow] = linv;
  __syncthreads();                              // all LDS dead; alias for ctx

  // ---- context epilogue: two half-rounds through a [64][66] alias ----
  {
    float* cst = (float*)smemraw;               // 16896 B
#pragma unroll 1
    for (int half = 0; half < 2; ++half) {
      if ((widx >> 2) == half) {
        const int lr = (widx & 3) * 16 + c;     // local row 0..63
#pragma unroll
        for (int nd = 0; nd < 4; ++nd) {
          float4v v;
#pragma unroll
          for (int r = 0; r < 4; ++r) v[r] = cacc[nd][r] * linv;
          *(float4v*)&cst[lr * 66 + nd * 16 + 4 * g] = v;
        }
      }
      __syncthreads();
      {
        const int qq = tid >> 3, ch = tid & 7;  // 64 rows x 8 floats
        const float* src = &cst[qq * 66 + ch * 8];
        float* dst = outC + ((size_t)(bh * S_ + q0 + half * 64 + qq)) * D_ + ch * 8;
        float4v c0 = *(const float4v*)src;
        float4v c1 = *(const float4v*)(src + 4);
        __builtin_nontemporal_store(c0, (float4v*)dst);
        __builtin_nontemporal_store(c1, (float4v*)(dst + 4));
      }
      __syncthreads();
    }
  }
}

// =============== Pass 2: QK -> exp -> xlinv -> full-line nt stores ===========
template <int PREP, int BM>
__global__ __launch_bounds__(256, 7) void k_store(
    const float* __restrict__ Q, const float* __restrict__ K,
    const float* __restrict__ scale_p, const uint8_t* __restrict__ M,
    const uint32_t* __restrict__ flag, const short* __restrict__ Kbf,
    const float* __restrict__ linvG, const uint32_t* __restrict__ mbitsG,
    float* __restrict__ outA)
{
  __shared__ uint32_t mbits2[64 * 68];          // stride 68, chunk-major rows
  __shared__ short eb2[4][16 * EBS];

  const int bx  = (blockIdx.x & 7) * 256 + (blockIdx.x >> 3);
  const int bh  = bx >> 5;
  const int q0  = (bx & 31) * 64;

  const int tid  = threadIdx.x;
  const int wv   = tid >> 6;
  const int lane = tid & 63;
  const int g    = lane >> 4;
  const int c    = lane & 15;
  const int qrow = q0 + wv * 16 + c;

  const float scale = scale_p[0];
  const uint32_t fl = flag[0];

  const short* Kbp = Kbf + (size_t)bh * S_ * D_;
  const float* Kfp = K + (size_t)bh * S_ * D_;

  // ---- bitmap prologue: 64 rows, 4 chunks (row-major within chunk in ws) ----
  if (BM) {
#pragma unroll
    for (int i = 0; i < 4; ++i) {
      const int j   = i * 256 + tid;            // uint4 index 0..1023
      const int cch = j >> 8;                   // chunk 0..3
      const int jj  = j & 255;
      const int row = jj >> 2, wi4 = (jj & 3) * 4;
      const uint32_t* mg = mbitsG + ((size_t)(bh * 4 + cch) * S_ + q0 + row) * 16 + wi4;
      uint4v v = *(const uint4v*)mg;
      *(uint4v*)&mbits2[row * 68 + cch * 16 + wi4] = v;
    }
  } else {
    const int row = tid >> 2;
    const int wq0 = (tid & 3) * 16;
    if (fl == 3u) {
      const uint8_t* mrow = M + ((size_t)(bh * S_ + q0 + row)) * S_ + wq0 * 32;
#pragma unroll
      for (int j = 0; j < 16; ++j) {
        uint4v a = *(const uint4v*)(mrow + j * 32);
        uint4v b = *(const uint4v*)(mrow + j * 32 + 16);
        mbits2[row * 68 + wq0 + j] =
            nib(a.x) | (nib(a.y) << 4) | (nib(a.z) << 8)  | (nib(a.w) << 12)
          | (nib(b.x) << 16) | (nib(b.y) << 20) | (nib(b.z) << 24) | (nib(b.w) << 28);
      }
    } else {
      const uint32_t* mrow = (const uint32_t*)M + ((size_t)(bh * S_ + q0 + row)) * S_ + wq0 * 32;
#pragma unroll
      for (int j = 0; j < 16; ++j) {
        uint32_t bits = 0;
#pragma unroll
        for (int u = 0; u < 8; ++u) {
          uint4v wvv = *(const uint4v*)(mrow + j * 32 + u * 4);
          uint32_t nzb = (wvv.x ? 1u : 0u) | (wvv.y ? 2u : 0u) | (wvv.z ? 4u : 0u) | (wvv.w ? 8u : 0u);
          bits |= nzb << (u * 4);
        }
        mbits2[row * 68 + wq0 + j] = bits;
      }
    }
  }

  // ---- Q as B-frag + per-row inverse sum (register) ----
  short8 qB[2];
  {
    const float* qr = Q + ((size_t)(bh * S_ + qrow)) * D_;
    float4v x0 = *(const float4v*)(qr + g * 8);
    float4v x1 = *(const float4v*)(qr + g * 8 + 4);
    float4v y0 = *(const float4v*)(qr + 32 + g * 8);
    float4v y1 = *(const float4v*)(qr + 32 + g * 8 + 4);
    short8 f;
    f[0]=f2bf(x0.x); f[1]=f2bf(x0.y); f[2]=f2bf(x0.z); f[3]=f2bf(x0.w);
    f[4]=f2bf(x1.x); f[5]=f2bf(x1.y); f[6]=f2bf(x1.z); f[7]=f2bf(x1.w);
    qB[0] = f;
    f[0]=f2bf(y0.x); f[1]=f2bf(y0.y); f[2]=f2bf(y0.z); f[3]=f2bf(y0.w);
    f[4]=f2bf(y1.x); f[5]=f2bf(y1.y); f[6]=f2bf(y1.z); f[7]=f2bf(y1.w);
    qB[1] = f;
  }
  const float linvq = linvG[(size_t)bh * S_ + qrow];
  __syncthreads();

  const uint32_t* mrow = &mbits2[(wv * 16 + c) * 68];   // linear w (chunk-major == linear)
  short* eb = &eb2[wv][0];
  const int srow = lane >> 3;
  const int scol = lane & 7;
  float* arow0 = outA + ((size_t)(bh * S_ + q0 + wv * 16 + srow)) * S_ + scol * 4;
  float* arow1 = outA + ((size_t)(bh * S_ + q0 + wv * 16 + srow + 8)) * S_ + scol * 4;

#pragma unroll 1
  for (int w = 0; w < NWIN; ++w) {
    const int kwin = w * 32;

    float4v acc0 = (float4v){0.f,0.f,0.f,0.f};
    float4v acc1 = (float4v){0.f,0.f,0.f,0.f};
    if (PREP) {
      const short* kr = Kbp + (size_t)(kwin + c) * D_ + g * 8;
      short8 a0 = *(const short8*)kr;
      short8 a1 = *(const short8*)(kr + 32);
      const short* kr1 = kr + 16 * D_;
      short8 a2 = *(const short8*)kr1;
      short8 a3 = *(const short8*)(kr1 + 32);
      acc0 = __builtin_amdgcn_mfma_f32_16x16x32_bf16(a0, qB[0], acc0, 0, 0, 0);
      acc0 = __builtin_amdgcn_mfma_f32_16x16x32_bf16(a1, qB[1], acc0, 0, 0, 0);
      acc1 = __builtin_amdgcn_mfma_f32_16x16x32_bf16(a2, qB[0], acc1, 0, 0, 0);
      acc1 = __builtin_amdgcn_mfma_f32_16x16x32_bf16(a3, qB[1], acc1, 0, 0, 0);
    } else {
      const float* kr = Kfp + (size_t)(kwin + c) * D_ + g * 8;
      const float* kr1 = kr + 16 * D_;
      short8 a0, a1, a2, a3;
#pragma unroll
      for (int e = 0; e < 8; ++e) {
        a0[e] = f2bf(kr[e]);  a1[e] = f2bf(kr[32 + e]);
        a2[e] = f2bf(kr1[e]); a3[e] = f2bf(kr1[32 + e]);
      }
      acc0 = __builtin_amdgcn_mfma_f32_16x16x32_bf16(a0, qB[0], acc0, 0, 0, 0);
      acc0 = __builtin_amdgcn_mfma_f32_16x16x32_bf16(a1, qB[1], acc0, 0, 0, 0);
      acc1 = __builtin_amdgcn_mfma_f32_16x16x32_bf16(a2, qB[0], acc1, 0, 0, 0);
      acc1 = __builtin_amdgcn_mfma_f32_16x16x32_bf16(a3, qB[1], acc1, 0, 0, 0);
    }

    const uint32_t mw = mrow[w];
    float n0[4], n1[4];
#pragma unroll
    for (int r = 0; r < 4; ++r) {
      n0[r] = (((mw >> (4 * g + r)) & 1u)      ? 1.0f : __expf(acc0[r] * scale)) * linvq;
      n1[r] = (((mw >> (16 + 4 * g + r)) & 1u) ? 1.0f : __expf(acc1[r] * scale)) * linvq;
    }
    uint2v lo, hi2;
    lo.x  = cvtpk(n0[0], n0[1]);  lo.y  = cvtpk(n0[2], n0[3]);
    hi2.x = cvtpk(n1[0], n1[1]);  hi2.y = cvtpk(n1[2], n1[3]);
    *(uint2v*)&eb[c * EBS + 4 * g]      = lo;
    *(uint2v*)&eb[c * EBS + 16 + 4 * g] = hi2;

    const uint2v ev0 = *(const uint2v*)&eb[srow * EBS + scol * 4];
    const uint2v ev1 = *(const uint2v*)&eb[(srow + 8) * EBS + scol * 4];
    float4v s0, s1;
    s0.x = bf2f(ev0.x & 0xffff); s0.y = bf2f(ev0.x >> 16);
    s0.z = bf2f(ev0.y & 0xffff); s0.w = bf2f(ev0.y >> 16);
    s1.x = bf2f(ev1.x & 0xffff); s1.y = bf2f(ev1.x >> 16);
    s1.z = bf2f(ev1.y & 0xffff); s1.w = bf2f(ev1.y >> 16);
    __builtin_nontemporal_store(s0, (float4v*)(arow0 + kwin));
    __builtin_nontemporal_store(s1, (float4v*)(arow1 + kwin));
  }
}

extern "C" void kernel_launch(void* const* d_in, const int* in_sizes, int n_in,
                              void* d_out, int out_size, void* d_ws, size_t ws_size,
                              hipStream_t stream) {
  const float*   Q     = (const float*)d_in[0];
  const float*   K     = (const float*)d_in[1];
  const float*   V     = (const float*)d_in[2];
  const float*   scale = (const float*)d_in[3];
  const uint8_t* M     = (const uint8_t*)d_in[4];
  uint32_t* flag  = (uint32_t*)d_ws;
  float*    linvG = (float*)((char*)d_ws + LINV_OFF);
  short*    Kbf   = (short*)((char*)d_ws + KBF_OFF);
  short*    VT    = (short*)((char*)d_ws + VT_OFF);
  uint32_t* mbG   = (uint32_t*)((char*)d_ws + MB_OFF);
  float* outC = (float*)d_out;
  float* outA = outC + (size_t)B_ * H_ * S_ * D_;

  hipMemsetAsync(flag, 0, 4, stream);
  detect_mask_dtype<<<dim3(1), dim3(256), 0, stream>>>(M, flag);

  const bool prep = ws_size >= VT_OFF + VT_BYTES;
  const bool bm   = ws_size >= MB_OFF + MB_BYTES;
  const int grid1 = B_ * H_ * (S_ / 128);       // 1024
  const int grid2 = B_ * H_ * (S_ / 64);        // 2048

  if (prep) {
    prep_k<<<dim3((B_ * H_ * S_ * D_) / (256 * 8)), dim3(256), 0, stream>>>(K, Kbf);
    prep_vt<<<dim3(B_ * H_ * (S_ / 64)), dim3(256), 0, stream>>>(V, VT);
    if (bm) {
      k_sums<1, 1><<<dim3(grid1), dim3(512), 0, stream>>>(
          Q, K, V, scale, M, flag, Kbf, VT, linvG, mbG, outC);
      k_store<1, 1><<<dim3(grid2), dim3(256), 0, stream>>>(
          Q, K, scale, M, flag, Kbf, linvG, mbG, outA);
    } else {
      k_sums<1, 0><<<dim3(grid1), dim3(512), 0, stream>>>(
          Q, K, V, scale, M, flag, Kbf, VT, linvG, mbG, outC);
      k_store<1, 0><<<dim3(grid2), dim3(256), 0, stream>>>(
          Q, K, scale, M, flag, Kbf, linvG, mbG, outA);
    }
  } else {
    k_sums<0, 0><<<dim3(grid1), dim3(512), 0, stream>>>(
        Q, K, V, scale, M, flag, Kbf, VT, linvG, mbG, outC);
    k_store<0, 0><<<dim3(grid2), dim3(256), 0, stream>>>(
        Q, K, scale, M, flag, Kbf, linvG, mbG, outA);
  }
}

// Round 20
// 845.327 us; speedup vs baseline: 1.3467x; 1.3467x over previous
//
#include <hip/hip_runtime.h>
#include <stdint.h>

#define B_ 4
#define H_ 16
#define S_ 2048
#define D_ 64
#define NWIN 64                       /* 32-k windows, full S */
#define EBS 40                        /* eb2 row stride (shorts), k_store only */
#define VBS 40                        /* vbuf row stride (shorts) */

typedef __attribute__((ext_vector_type(8))) short short8;
typedef __attribute__((ext_vector_type(4))) float float4v;
typedef __attribute__((ext_vector_type(4))) unsigned int uint4v;
typedef __attribute__((ext_vector_type(2))) unsigned int uint2v;

static __device__ __forceinline__ short f2bf(float f) {
  uint32_t u = __builtin_bit_cast(uint32_t, f);
  u = (u + 0x7FFFu + ((u >> 16) & 1u)) >> 16;   // RNE
  return (short)u;
}
static __device__ __forceinline__ float bf2f(uint32_t s) {
  return __builtin_bit_cast(float, s << 16);
}
static __device__ __forceinline__ uint32_t cvtpk(float lo, float hi) {
  uint32_t r;
  asm("v_cvt_pk_bf16_f32 %0, %1, %2" : "=v"(r) : "v"(lo), "v"(hi));
  return r;
}
static __device__ __forceinline__ uint32_t nz4(uint32_t d) {
  uint32_t x = (d & 0x7F7F7F7Fu) + 0x7F7F7F7Fu;
  x = (x | d) & 0x80808080u;
  return x >> 7;
}
static __device__ __forceinline__ uint32_t nib(uint32_t d) {
  return ((nz4(d) * 0x01020408u) >> 24) & 0xFu;
}

// workspace layout
#define LINV_OFF   ((size_t)64)
#define LINV_BYTES ((size_t)B_ * H_ * S_ * 4)
#define KBF_OFF    (LINV_OFF + LINV_BYTES)
#define KBF_BYTES  ((size_t)B_ * H_ * S_ * D_ * 2)
#define VT_OFF     (KBF_OFF + KBF_BYTES)
#define VT_BYTES   ((size_t)B_ * H_ * S_ * D_ * 2)
#define MB_OFF     (VT_OFF + VT_BYTES)
#define MB_BYTES   ((size_t)B_ * H_ * S_ * 64 * 4)

__global__ void detect_mask_dtype(const uint8_t* __restrict__ m, uint32_t* flag) {
  uint32_t a = 0, b = 0;
  for (int i = threadIdx.x; i < 65536; i += 256) {
    uint8_t x = m[i];
    if (i & 3) a |= x; else b |= x;
  }
  uint32_t bits = (a ? 1u : 0u) | (b ? 2u : 0u);
  if (bits) atomicOr(flag, bits);
}

__global__ __launch_bounds__(256) void prep_k(const float* __restrict__ K,
                                              short* __restrict__ Kbf) {
  size_t base = ((size_t)blockIdx.x * 256 + threadIdx.x) * 8;
  float4v a = *(const float4v*)(K + base);
  float4v b = *(const float4v*)(K + base + 4);
  short8 o;
  o[0]=f2bf(a.x); o[1]=f2bf(a.y); o[2]=f2bf(a.z); o[3]=f2bf(a.w);
  o[4]=f2bf(b.x); o[5]=f2bf(b.y); o[6]=f2bf(b.z); o[7]=f2bf(b.w);
  *(short8*)(Kbf + base) = o;
}

__global__ __launch_bounds__(256) void prep_vt(const float* __restrict__ V,
                                               short* __restrict__ VT) {
  __shared__ short tile[64][72];
  int bh = blockIdx.x >> 5, k0 = (blockIdx.x & 31) * 64;
  const float* src = V + ((size_t)bh * S_ + k0) * D_;
  int t = threadIdx.x;
  int r = t >> 2, c0 = (t & 3) * 16;
#pragma unroll
  for (int j = 0; j < 4; ++j) {
    float4v f = *(const float4v*)(src + (size_t)r * D_ + c0 + j * 4);
    tile[r][c0 + j*4 + 0] = f2bf(f.x);
    tile[r][c0 + j*4 + 1] = f2bf(f.y);
    tile[r][c0 + j*4 + 2] = f2bf(f.z);
    tile[r][c0 + j*4 + 3] = f2bf(f.w);
  }
  __syncthreads();
  int d = t >> 2, ks0 = (t & 3) * 16;
  short* dst = VT + (size_t)bh * D_ * S_ + (size_t)d * S_ + k0 + ks0;
#pragma unroll
  for (int half = 0; half < 2; ++half) {
    short8 o;
#pragma unroll
    for (int i = 0; i < 8; ++i) o[i] = tile[ks0 + half * 8 + i][d];
    *(short8*)(dst + half * 8) = o;
  }
}

// === Pass 1: rowsums + PV + context; K,V LDS-relayed; PV frag via shuffles ===
template <int PREP, int BM>
__global__ __launch_bounds__(512, 6) void k_sums(
    const float* __restrict__ Q, const float* __restrict__ K,
    const float* __restrict__ V, const float* __restrict__ scale_p,
    const uint8_t* __restrict__ M, const uint32_t* __restrict__ flag,
    const short* __restrict__ Kbf, const short* __restrict__ VT,
    float* __restrict__ linvG, uint32_t* __restrict__ mbitsG,
    float* __restrict__ outC)
{
  __shared__ uint32_t mbits[128 * 66];          // mask stride 65; ctx-alias stride 66
  __shared__ short kbuf[2][32 * 64];            // K window dbuf (XOR-swizzled)
  __shared__ short vbuf[2][64 * VBS];           // V window dbuf [d][k] (padded)
  // total 52224 B -> 3 blocks/CU, 24 waves

  const int bx  = (blockIdx.x & 7) * 128 + (blockIdx.x >> 3);
  const int bh  = bx >> 4;
  const int q0  = (bx & 15) * 128;

  const int tid  = threadIdx.x;
  const int widx = tid >> 6;
  const int lane = tid & 63;
  const int g    = lane >> 4;
  const int c    = lane & 15;
  const int qrow = q0 + widx * 16 + c;

  const float scale = scale_p[0];
  const uint32_t fl = flag[0];

  const short* Kbp = Kbf + (size_t)bh * S_ * D_;
  const short* VTp = VT + (size_t)bh * D_ * S_;
  const float* Kfp = K + (size_t)bh * S_ * D_;
  const float* Vfp = V + (size_t)bh * S_ * D_;

  // ---- mask bitmap prologue: [128][2048] bits (stride 65), PLAIN loads ----
  {
    const int row = tid >> 2;
    const int wq0 = (tid & 3) * 16;
    if (fl == 3u) {
      const uint8_t* mrow = M + ((size_t)(bh * S_ + q0 + row)) * S_ + wq0 * 32;
#pragma unroll
      for (int j = 0; j < 16; ++j) {
        uint4v a = *(const uint4v*)(mrow + j * 32);
        uint4v b = *(const uint4v*)(mrow + j * 32 + 16);
        mbits[row * 65 + wq0 + j] =
            nib(a.x) | (nib(a.y) << 4) | (nib(a.z) << 8)  | (nib(a.w) << 12)
          | (nib(b.x) << 16) | (nib(b.y) << 20) | (nib(b.z) << 24) | (nib(b.w) << 28);
      }
    } else {
      const uint32_t* mrow = (const uint32_t*)M + ((size_t)(bh * S_ + q0 + row)) * S_ + wq0 * 32;
#pragma unroll
      for (int j = 0; j < 16; ++j) {
        uint32_t bits = 0;
#pragma unroll
        for (int u = 0; u < 8; ++u) {
          uint4v wv = *(const uint4v*)(mrow + j * 32 + u * 4);
          uint32_t nzb = (wv.x ? 1u : 0u) | (wv.y ? 2u : 0u) | (wv.z ? 4u : 0u) | (wv.w ? 8u : 0u);
          bits |= nzb << (u * 4);
        }
        mbits[row * 65 + wq0 + j] = bits;
      }
    }
  }

  // ---- Q as B-frag: lane holds Q[qrow][.] ----
  short8 qB[2];
  {
    const float* qr = Q + ((size_t)(bh * S_ + qrow)) * D_;
    float4v x0 = *(const float4v*)(qr + g * 8);
    float4v x1 = *(const float4v*)(qr + g * 8 + 4);
    float4v y0 = *(const float4v*)(qr + 32 + g * 8);
    float4v y1 = *(const float4v*)(qr + 32 + g * 8 + 4);
    short8 f;
    f[0]=f2bf(x0.x); f[1]=f2bf(x0.y); f[2]=f2bf(x0.z); f[3]=f2bf(x0.w);
    f[4]=f2bf(x1.x); f[5]=f2bf(x1.y); f[6]=f2bf(x1.z); f[7]=f2bf(x1.w);
    qB[0] = f;
    f[0]=f2bf(y0.x); f[1]=f2bf(y0.y); f[2]=f2bf(y0.z); f[3]=f2bf(y0.w);
    f[4]=f2bf(y1.x); f[5]=f2bf(y1.y); f[6]=f2bf(y1.z); f[7]=f2bf(y1.w);
    qB[1] = f;
  }

  // ---- staging: waves 0-3 relay K (XOR-swizzled), waves 4-7 relay V ----
  const bool kstager = (widx < 4);
  const bool vstager = (widx >= 4) && (PREP != 0);
  const int  sr = (widx << 3) + (lane >> 3);
  const int  sp = lane & 7;
  const int  sdst = sr * 64 + ((sp ^ (sr & 7)) << 3);
  const int  vr = ((widx - 4) << 4) + (lane >> 2);
  const int  vp = lane & 3;
  short8  kreg, vreg;
  float4v kf0, kf1;
#define ISSUE(W) do {                                                          \
    if (kstager) {                                                             \
      if (PREP) kreg = *(const short8*)(Kbp + (size_t)((W) * 32 + sr) * 64 + sp * 8); \
      else { const float* s_ = Kfp + (size_t)((W) * 32 + sr) * 64 + sp * 8;    \
             kf0 = *(const float4v*)s_; kf1 = *(const float4v*)(s_ + 4); }     \
    } else if (vstager) {                                                      \
      vreg = *(const short8*)(VTp + (size_t)vr * S_ + (W) * 32 + vp * 8);      \
    } } while (0)
#define WRITE(BUF) do {                                                        \
    if (kstager) {                                                             \
      short8 o_;                                                               \
      if (PREP) o_ = kreg;                                                     \
      else { o_[0]=f2bf(kf0.x); o_[1]=f2bf(kf0.y); o_[2]=f2bf(kf0.z); o_[3]=f2bf(kf0.w); \
             o_[4]=f2bf(kf1.x); o_[5]=f2bf(kf1.y); o_[6]=f2bf(kf1.z); o_[7]=f2bf(kf1.w); } \
      *(short8*)&kbuf[BUF][sdst] = o_;                                         \
    } else if (vstager) {                                                      \
      *(short8*)&vbuf[BUF][vr * VBS + vp * 8] = vreg;                          \
    } } while (0)

  const int ka0 = ((g       ^ (c & 7)) << 3);
  const int ka1 = (((g + 4) ^ (c & 7)) << 3);
  const uint32_t* mrow = &mbits[(widx * 16 + c) * 65];
  const int srcA = ((2 * g) & 3) * 16 + c;      // shuffle-transpose sources (R5)
  const int srcB = srcA + 16;
  const bool hi = g >= 2;

  ISSUE(0); WRITE(0); ISSUE(1);
  __syncthreads();

  // ---- bitmap dump: linear, full-line NT stores ----
  if (BM) {
    uint32_t* mg = mbitsG + ((size_t)(bh * S_ + q0)) * 64;
#pragma unroll
    for (int i = 0; i < 16; ++i) {
      const int wdx = i * 512 + tid;
      const int row = wdx >> 6, wir = wdx & 63;
      __builtin_nontemporal_store(mbits[row * 65 + wir], mg + wdx);
    }
  }

  float rsv = 0.0f;
  float4v cacc[4];
#pragma unroll
  for (int nd = 0; nd < 4; ++nd) cacc[nd] = (float4v){0.f, 0.f, 0.f, 0.f};

#pragma unroll 1
  for (int w = 0; w < NWIN; ++w) {
    const int cur = w & 1;
    const int kwin = w * 32;

    short8 vA0, vA1, vA2, vA3;
    if (PREP) {
      const short* vb = &vbuf[cur][0];
      vA0 = *(const short8*)(vb + (size_t)(c)      * VBS + g * 8);
      vA1 = *(const short8*)(vb + (size_t)(16 + c) * VBS + g * 8);
      vA2 = *(const short8*)(vb + (size_t)(32 + c) * VBS + g * 8);
      vA3 = *(const short8*)(vb + (size_t)(48 + c) * VBS + g * 8);
    } else {
      const float* vc = Vfp + (size_t)(kwin + g * 8) * D_ + c;
#pragma unroll
      for (int e = 0; e < 8; ++e) {
        vA0[e] = f2bf(vc[(size_t)e * D_]);
        vA1[e] = f2bf(vc[(size_t)e * D_ + 16]);
        vA2[e] = f2bf(vc[(size_t)e * D_ + 32]);
        vA3[e] = f2bf(vc[(size_t)e * D_ + 48]);
      }
    }

    const short* kb = &kbuf[cur][0];
    short8 a0 = *(const short8*)(kb + c * 64 + ka0);
    short8 a1 = *(const short8*)(kb + c * 64 + ka1);
    short8 a2 = *(const short8*)(kb + (c + 16) * 64 + ka0);
    short8 a3 = *(const short8*)(kb + (c + 16) * 64 + ka1);

    float4v acc0 = (float4v){0.f,0.f,0.f,0.f};
    float4v acc1 = (float4v){0.f,0.f,0.f,0.f};
    acc0 = __builtin_amdgcn_mfma_f32_16x16x32_bf16(a0, qB[0], acc0, 0, 0, 0);
    acc0 = __builtin_amdgcn_mfma_f32_16x16x32_bf16(a1, qB[1], acc0, 0, 0, 0);
    acc1 = __builtin_amdgcn_mfma_f32_16x16x32_bf16(a2, qB[0], acc1, 0, 0, 0);
    acc1 = __builtin_amdgcn_mfma_f32_16x16x32_bf16(a3, qB[1], acc1, 0, 0, 0);

    const uint32_t mw = mrow[w];
    float e0[4], e1[4];
#pragma unroll
    for (int r = 0; r < 4; ++r) {
      e0[r] = ((mw >> (4 * g + r)) & 1u)      ? 1.0f : __expf(acc0[r] * scale);
      e1[r] = ((mw >> (16 + 4 * g + r)) & 1u) ? 1.0f : __expf(acc1[r] * scale);
      rsv += e0[r] + e1[r];
    }
    // pack E to bf16 and shuffle-transpose into the PV B-frag (no LDS)
    uint32_t es0 = cvtpk(e0[0], e0[1]), es1 = cvtpk(e0[2], e0[3]);
    uint32_t es2 = cvtpk(e1[0], e1[1]), es3 = cvtpk(e1[2], e1[3]);
    uint32_t x0 = __shfl(es0, srcA), y0 = __shfl(es2, srcA);
    uint32_t x1 = __shfl(es1, srcA), y1 = __shfl(es3, srcA);
    uint32_t x2 = __shfl(es0, srcB), y2 = __shfl(es2, srcB);
    uint32_t x3 = __shfl(es1, srcB), y3 = __shfl(es3, srcB);
    uint4v bb;
    bb.x = hi ? y0 : x0;
    bb.y = hi ? y1 : x1;
    bb.z = hi ? y2 : x2;
    bb.w = hi ? y3 : x3;
    const short8 bfrag = __builtin_bit_cast(short8, bb);

    cacc[0] = __builtin_amdgcn_mfma_f32_16x16x32_bf16(vA0, bfrag, cacc[0], 0, 0, 0);
    cacc[1] = __builtin_amdgcn_mfma_f32_16x16x32_bf16(vA1, bfrag, cacc[1], 0, 0, 0);
    cacc[2] = __builtin_amdgcn_mfma_f32_16x16x32_bf16(vA2, bfrag, cacc[2], 0, 0, 0);
    cacc[3] = __builtin_amdgcn_mfma_f32_16x16x32_bf16(vA3, bfrag, cacc[3], 0, 0, 0);

    if (w + 1 < NWIN) {
      WRITE(cur ^ 1);
      if (w + 2 < NWIN) ISSUE(w + 2);
      __syncthreads();
    }
  }
#undef ISSUE
#undef WRITE

  rsv += __shfl_xor(rsv, 16);
  rsv += __shfl_xor(rsv, 32);
  const float linv = 1.0f / rsv;
  if (g == 0) linvG[(size_t)bh * S_ + qrow] = linv;
  __syncthreads();                              // mask dead; alias mbits for ctx

  // ---- context epilogue: normalize cacc, LDS transpose (stride 66), store ----
  {
    float* cst = (float*)mbits;                 // [128][66] floats
#pragma unroll
    for (int nd = 0; nd < 4; ++nd) {
      float4v v;
#pragma unroll
      for (int r = 0; r < 4; ++r) v[r] = cacc[nd][r] * linv;
      *(float4v*)&cst[(widx * 16 + c) * 66 + nd * 16 + 4 * g] = v;
    }
    __syncthreads();
    const int qq = tid >> 2, ch = tid & 3;
    const float* src = &cst[qq * 66 + ch * 16];
    float* dst = outC + ((size_t)(bh * S_ + q0 + qq)) * D_ + ch * 16;
    float4v c0 = *(const float4v*)src;
    float4v c1 = *(const float4v*)(src + 4);
    float4v c2 = *(const float4v*)(src + 8);
    float4v c3 = *(const float4v*)(src + 12);
    __builtin_nontemporal_store(c0, (float4v*)dst);
    __builtin_nontemporal_store(c1, (float4v*)(dst + 4));
    __builtin_nontemporal_store(c2, (float4v*)(dst + 8));
    __builtin_nontemporal_store(c3, (float4v*)(dst + 12));
  }
}

// =============== Pass 2: QK -> exp -> xlinv -> full-line nt stores ===========
template <int PREP, int BM>
__global__ __launch_bounds__(256, 7) void k_store(
    const float* __restrict__ Q, const float* __restrict__ K,
    const float* __restrict__ scale_p, const uint8_t* __restrict__ M,
    const uint32_t* __restrict__ flag, const short* __restrict__ Kbf,
    const float* __restrict__ linvG, const uint32_t* __restrict__ mbitsG,
    float* __restrict__ outA)
{
  __shared__ uint32_t mbits2[64 * 68];          // stride 68 (16B-aligned rows)
  __shared__ short eb2[4][16 * EBS];

  const int bx  = (blockIdx.x & 7) * 256 + (blockIdx.x >> 3);
  const int bh  = bx >> 5;
  const int q0  = (bx & 31) * 64;

  const int tid  = threadIdx.x;
  const int wv   = tid >> 6;
  const int lane = tid & 63;
  const int g    = lane >> 4;
  const int c    = lane & 15;
  const int qrow = q0 + wv * 16 + c;

  const float scale = scale_p[0];
  const uint32_t fl = flag[0];

  const short* Kbp = Kbf + (size_t)bh * S_ * D_;
  const float* Kfp = K + (size_t)bh * S_ * D_;

  // ---- bitmap prologue: 64 rows (stride 68) ----
  if (BM) {
    const uint32_t* mg = mbitsG + ((size_t)(bh * S_ + q0)) * 64;
#pragma unroll
    for (int i = 0; i < 4; ++i) {
      const int idx4 = i * 256 + tid;
      uint4v v = *(const uint4v*)(mg + (size_t)idx4 * 4);
      const int w0 = idx4 * 4, row = w0 >> 6, wir = w0 & 63;
      *(uint4v*)&mbits2[row * 68 + wir] = v;
    }
  } else {
    const int row = tid >> 2;
    const int wq0 = (tid & 3) * 16;
    if (fl == 3u) {
      const uint8_t* mrow = M + ((size_t)(bh * S_ + q0 + row)) * S_ + wq0 * 32;
#pragma unroll
      for (int j = 0; j < 16; ++j) {
        uint4v a = *(const uint4v*)(mrow + j * 32);
        uint4v b = *(const uint4v*)(mrow + j * 32 + 16);
        mbits2[row * 68 + wq0 + j] =
            nib(a.x) | (nib(a.y) << 4) | (nib(a.z) << 8)  | (nib(a.w) << 12)
          | (nib(b.x) << 16) | (nib(b.y) << 20) | (nib(b.z) << 24) | (nib(b.w) << 28);
      }
    } else {
      const uint32_t* mrow = (const uint32_t*)M + ((size_t)(bh * S_ + q0 + row)) * S_ + wq0 * 32;
#pragma unroll
      for (int j = 0; j < 16; ++j) {
        uint32_t bits = 0;
#pragma unroll
        for (int u = 0; u < 8; ++u) {
          uint4v wvv = *(const uint4v*)(mrow + j * 32 + u * 4);
          uint32_t nzb = (wvv.x ? 1u : 0u) | (wvv.y ? 2u : 0u) | (wvv.z ? 4u : 0u) | (wvv.w ? 8u : 0u);
          bits |= nzb << (u * 4);
        }
        mbits2[row * 68 + wq0 + j] = bits;
      }
    }
  }

  // ---- Q as B-frag + per-row inverse sum (register) ----
  short8 qB[2];
  {
    const float* qr = Q + ((size_t)(bh * S_ + qrow)) * D_;
    float4v x0 = *(const float4v*)(qr + g * 8);
    float4v x1 = *(const float4v*)(qr + g * 8 + 4);
    float4v y0 = *(const float4v*)(qr + 32 + g * 8);
    float4v y1 = *(const float4v*)(qr + 32 + g * 8 + 4);
    short8 f;
    f[0]=f2bf(x0.x); f[1]=f2bf(x0.y); f[2]=f2bf(x0.z); f[3]=f2bf(x0.w);
    f[4]=f2bf(x1.x); f[5]=f2bf(x1.y); f[6]=f2bf(x1.z); f[7]=f2bf(x1.w);
    qB[0] = f;
    f[0]=f2bf(y0.x); f[1]=f2bf(y0.y); f[2]=f2bf(y0.z); f[3]=f2bf(y0.w);
    f[4]=f2bf(y1.x); f[5]=f2bf(y1.y); f[6]=f2bf(y1.z); f[7]=f2bf(y1.w);
    qB[1] = f;
  }
  const float linvq = linvG[(size_t)bh * S_ + qrow];
  __syncthreads();

  const uint32_t* mrow = &mbits2[(wv * 16 + c) * 68];
  short* eb = &eb2[wv][0];
  const int srow = lane >> 3;
  const int scol = lane & 7;
  float* arow0 = outA + ((size_t)(bh * S_ + q0 + wv * 16 + srow)) * S_ + scol * 4;
  float* arow1 = outA + ((size_t)(bh * S_ + q0 + wv * 16 + srow + 8)) * S_ + scol * 4;

#pragma unroll 1
  for (int w = 0; w < NWIN; ++w) {
    const int kwin = w * 32;

    float4v acc0 = (float4v){0.f,0.f,0.f,0.f};
    float4v acc1 = (float4v){0.f,0.f,0.f,0.f};
    if (PREP) {
      const short* kr = Kbp + (size_t)(kwin + c) * D_ + g * 8;
      short8 a0 = *(const short8*)kr;
      short8 a1 = *(const short8*)(kr + 32);
      const short* kr1 = kr + 16 * D_;
      short8 a2 = *(const short8*)kr1;
      short8 a3 = *(const short8*)(kr1 + 32);
      acc0 = __builtin_amdgcn_mfma_f32_16x16x32_bf16(a0, qB[0], acc0, 0, 0, 0);
      acc0 = __builtin_amdgcn_mfma_f32_16x16x32_bf16(a1, qB[1], acc0, 0, 0, 0);
      acc1 = __builtin_amdgcn_mfma_f32_16x16x32_bf16(a2, qB[0], acc1, 0, 0, 0);
      acc1 = __builtin_amdgcn_mfma_f32_16x16x32_bf16(a3, qB[1], acc1, 0, 0, 0);
    } else {
      const float* kr = Kfp + (size_t)(kwin + c) * D_ + g * 8;
      const float* kr1 = kr + 16 * D_;
      short8 a0, a1, a2, a3;
#pragma unroll
      for (int e = 0; e < 8; ++e) {
        a0[e] = f2bf(kr[e]);  a1[e] = f2bf(kr[32 + e]);
        a2[e] = f2bf(kr1[e]); a3[e] = f2bf(kr1[32 + e]);
      }
      acc0 = __builtin_amdgcn_mfma_f32_16x16x32_bf16(a0, qB[0], acc0, 0, 0, 0);
      acc0 = __builtin_amdgcn_mfma_f32_16x16x32_bf16(a1, qB[1], acc0, 0, 0, 0);
      acc1 = __builtin_amdgcn_mfma_f32_16x16x32_bf16(a2, qB[0], acc1, 0, 0, 0);
      acc1 = __builtin_amdgcn_mfma_f32_16x16x32_bf16(a3, qB[1], acc1, 0, 0, 0);
    }

    const uint32_t mw = mrow[w];
    float n0[4], n1[4];
#pragma unroll
    for (int r = 0; r < 4; ++r) {
      n0[r] = (((mw >> (4 * g + r)) & 1u)      ? 1.0f : __expf(acc0[r] * scale)) * linvq;
      n1[r] = (((mw >> (16 + 4 * g + r)) & 1u) ? 1.0f : __expf(acc1[r] * scale)) * linvq;
    }
    uint2v lo, hi2;
    lo.x  = cvtpk(n0[0], n0[1]);  lo.y  = cvtpk(n0[2], n0[3]);
    hi2.x = cvtpk(n1[0], n1[1]);  hi2.y = cvtpk(n1[2], n1[3]);
    *(uint2v*)&eb[c * EBS + 4 * g]      = lo;
    *(uint2v*)&eb[c * EBS + 16 + 4 * g] = hi2;

    const uint2v ev0 = *(const uint2v*)&eb[srow * EBS + scol * 4];
    const uint2v ev1 = *(const uint2v*)&eb[(srow + 8) * EBS + scol * 4];
    float4v s0, s1;
    s0.x = bf2f(ev0.x & 0xffff); s0.y = bf2f(ev0.x >> 16);
    s0.z = bf2f(ev0.y & 0xffff); s0.w = bf2f(ev0.y >> 16);
    s1.x = bf2f(ev1.x & 0xffff); s1.y = bf2f(ev1.x >> 16);
    s1.z = bf2f(ev1.y & 0xffff); s1.w = bf2f(ev1.y >> 16);
    __builtin_nontemporal_store(s0, (float4v*)(arow0 + kwin));
    __builtin_nontemporal_store(s1, (float4v*)(arow1 + kwin));
  }
}

extern "C" void kernel_launch(void* const* d_in, const int* in_sizes, int n_in,
                              void* d_out, int out_size, void* d_ws, size_t ws_size,
                              hipStream_t stream) {
  const float*   Q     = (const float*)d_in[0];
  const float*   K     = (const float*)d_in[1];
  const float*   V     = (const float*)d_in[2];
  const float*   scale = (const float*)d_in[3];
  const uint8_t* M     = (const uint8_t*)d_in[4];
  uint32_t* flag  = (uint32_t*)d_ws;
  float*    linvG = (float*)((char*)d_ws + LINV_OFF);
  short*    Kbf   = (short*)((char*)d_ws + KBF_OFF);
  short*    VT    = (short*)((char*)d_ws + VT_OFF);
  uint32_t* mbG   = (uint32_t*)((char*)d_ws + MB_OFF);
  float* outC = (float*)d_out;
  float* outA = outC + (size_t)B_ * H_ * S_ * D_;

  hipMemsetAsync(flag, 0, 4, stream);
  detect_mask_dtype<<<dim3(1), dim3(256), 0, stream>>>(M, flag);

  const bool prep = ws_size >= VT_OFF + VT_BYTES;
  const bool bm   = ws_size >= MB_OFF + MB_BYTES;
  const int grid1 = B_ * H_ * (S_ / 128);       // 1024
  const int grid2 = B_ * H_ * (S_ / 64);        // 2048

  if (prep) {
    prep_k<<<dim3((B_ * H_ * S_ * D_) / (256 * 8)), dim3(256), 0, stream>>>(K, Kbf);
    prep_vt<<<dim3(B_ * H_ * (S_ / 64)), dim3(256), 0, stream>>>(V, VT);
    if (bm) {
      k_sums<1, 1><<<dim3(grid1), dim3(512), 0, stream>>>(
          Q, K, V, scale, M, flag, Kbf, VT, linvG, mbG, outC);
      k_store<1, 1><<<dim3(grid2), dim3(256), 0, stream>>>(
          Q, K, scale, M, flag, Kbf, linvG, mbG, outA);
    } else {
      k_sums<1, 0><<<dim3(grid1), dim3(512), 0, stream>>>(
          Q, K, V, scale, M, flag, Kbf, VT, linvG, mbG, outC);
      k_store<1, 0><<<dim3(grid2), dim3(256), 0, stream>>>(
          Q, K, scale, M, flag, Kbf, linvG, mbG, outA);
    }
  } else {
    k_sums<0, 0><<<dim3(grid1), dim3(512), 0, stream>>>(
        Q, K, V, scale, M, flag, Kbf, VT, linvG, mbG, outC);
    k_store<0, 0><<<dim3(grid2), dim3(256), 0, stream>>>(
        Q, K, scale, M, flag, Kbf, linvG, mbG, outA);
  }
}

// Round 21
// 822.111 us; speedup vs baseline: 1.3847x; 1.0282x over previous
//
#include <hip/hip_runtime.h>
#include <stdint.h>

#define B_ 4
#define H_ 16
#define S_ 2048
#define D_ 64
#define NWIN 64                       /* 32-k windows, full S */
#define EBS 40                        /* ebounce row stride (shorts) */
#define VBS 40                        /* vbuf row stride (shorts) */

typedef __attribute__((ext_vector_type(8))) short short8;
typedef __attribute__((ext_vector_type(4))) float float4v;
typedef __attribute__((ext_vector_type(4))) unsigned int uint4v;
typedef __attribute__((ext_vector_type(2))) unsigned int uint2v;

static __device__ __forceinline__ short f2bf(float f) {
  uint32_t u = __builtin_bit_cast(uint32_t, f);
  u = (u + 0x7FFFu + ((u >> 16) & 1u)) >> 16;   // RNE
  return (short)u;
}
static __device__ __forceinline__ float bf2f(uint32_t s) {
  return __builtin_bit_cast(float, s << 16);
}
static __device__ __forceinline__ uint32_t cvtpk(float lo, float hi) {
  uint32_t r;
  asm("v_cvt_pk_bf16_f32 %0, %1, %2" : "=v"(r) : "v"(lo), "v"(hi));
  return r;
}
static __device__ __forceinline__ uint32_t nz4(uint32_t d) {
  uint32_t x = (d & 0x7F7F7F7Fu) + 0x7F7F7F7Fu;
  x = (x | d) & 0x80808080u;
  return x >> 7;
}
static __device__ __forceinline__ uint32_t nib(uint32_t d) {
  return ((nz4(d) * 0x01020408u) >> 24) & 0xFu;
}

// workspace layout
#define LINV_OFF   ((size_t)64)
#define LINV_BYTES ((size_t)B_ * H_ * S_ * 4)
#define KBF_OFF    (LINV_OFF + LINV_BYTES)
#define KBF_BYTES  ((size_t)B_ * H_ * S_ * D_ * 2)
#define VT_OFF     (KBF_OFF + KBF_BYTES)
#define VT_BYTES   ((size_t)B_ * H_ * S_ * D_ * 2)
#define MB_OFF     (VT_OFF + VT_BYTES)
#define MB_BYTES   ((size_t)B_ * H_ * S_ * 64 * 4)

__global__ void detect_mask_dtype(const uint8_t* __restrict__ m, uint32_t* flag) {
  uint32_t a = 0, b = 0;
  for (int i = threadIdx.x; i < 65536; i += 256) {
    uint8_t x = m[i];
    if (i & 3) a |= x; else b |= x;
  }
  uint32_t bits = (a ? 1u : 0u) | (b ? 2u : 0u);
  if (bits) atomicOr(flag, bits);
}

__global__ __launch_bounds__(256) void prep_k(const float* __restrict__ K,
                                              short* __restrict__ Kbf) {
  size_t base = ((size_t)blockIdx.x * 256 + threadIdx.x) * 8;
  float4v a = *(const float4v*)(K + base);
  float4v b = *(const float4v*)(K + base + 4);
  short8 o;
  o[0]=f2bf(a.x); o[1]=f2bf(a.y); o[2]=f2bf(a.z); o[3]=f2bf(a.w);
  o[4]=f2bf(b.x); o[5]=f2bf(b.y); o[6]=f2bf(b.z); o[7]=f2bf(b.w);
  *(short8*)(Kbf + base) = o;
}

__global__ __launch_bounds__(256) void prep_vt(const float* __restrict__ V,
                                               short* __restrict__ VT) {
  __shared__ short tile[64][72];
  int bh = blockIdx.x >> 5, k0 = (blockIdx.x & 31) * 64;
  const float* src = V + ((size_t)bh * S_ + k0) * D_;
  int t = threadIdx.x;
  int r = t >> 2, c0 = (t & 3) * 16;
#pragma unroll
  for (int j = 0; j < 4; ++j) {
    float4v f = *(const float4v*)(src + (size_t)r * D_ + c0 + j * 4);
    tile[r][c0 + j*4 + 0] = f2bf(f.x);
    tile[r][c0 + j*4 + 1] = f2bf(f.y);
    tile[r][c0 + j*4 + 2] = f2bf(f.z);
    tile[r][c0 + j*4 + 3] = f2bf(f.w);
  }
  __syncthreads();
  int d = t >> 2, ks0 = (t & 3) * 16;
  short* dst = VT + (size_t)bh * D_ * S_ + (size_t)d * S_ + k0 + ks0;
#pragma unroll
  for (int half = 0; half < 2; ++half) {
    short8 o;
#pragma unroll
    for (int i = 0; i < 8; ++i) o[i] = tile[ks0 + half * 8 + i][d];
    *(short8*)(dst + half * 8) = o;
  }
}

// === Pass 1: rowsums (-> linvG) + PV + context; K AND V LDS-relayed ==========
template <int PREP, int BM>
__global__ __launch_bounds__(512, 6) void k_sums(
    const float* __restrict__ Q, const float* __restrict__ K,
    const float* __restrict__ V, const float* __restrict__ scale_p,
    const uint8_t* __restrict__ M, const uint32_t* __restrict__ flag,
    const short* __restrict__ Kbf, const short* __restrict__ VT,
    float* __restrict__ linvG, uint32_t* __restrict__ mbitsG,
    float* __restrict__ outC)
{
  __shared__ uint32_t mbits[128 * 66];          // mask stride 65; ctx-alias stride 66
  __shared__ short kbuf[2][32 * 64];            // K window dbuf (XOR-swizzled)
  __shared__ short vbuf[2][64 * VBS];           // V window dbuf [d][k] (padded)
  __shared__ short ebounce[8][16 * EBS];        // per-wave E bounce

  const int bx  = (blockIdx.x & 7) * 128 + (blockIdx.x >> 3);
  const int bh  = bx >> 4;
  const int q0  = (bx & 15) * 128;

  const int tid  = threadIdx.x;
  const int widx = tid >> 6;
  const int lane = tid & 63;
  const int g    = lane >> 4;
  const int c    = lane & 15;
  const int qrow = q0 + widx * 16 + c;

  const float scale = scale_p[0];
  const uint32_t fl = flag[0];

  const short* Kbp = Kbf + (size_t)bh * S_ * D_;
  const short* VTp = VT + (size_t)bh * D_ * S_;
  const float* Kfp = K + (size_t)bh * S_ * D_;
  const float* Vfp = V + (size_t)bh * S_ * D_;

  // ---- mask bitmap prologue: [128][2048] bits (stride 65), PLAIN loads ----
  {
    const int row = tid >> 2;
    const int wq0 = (tid & 3) * 16;
    if (fl == 3u) {
      const uint8_t* mrow = M + ((size_t)(bh * S_ + q0 + row)) * S_ + wq0 * 32;
#pragma unroll
      for (int j = 0; j < 16; ++j) {
        uint4v a = *(const uint4v*)(mrow + j * 32);
        uint4v b = *(const uint4v*)(mrow + j * 32 + 16);
        mbits[row * 65 + wq0 + j] =
            nib(a.x) | (nib(a.y) << 4) | (nib(a.z) << 8)  | (nib(a.w) << 12)
          | (nib(b.x) << 16) | (nib(b.y) << 20) | (nib(b.z) << 24) | (nib(b.w) << 28);
      }
    } else {
      const uint32_t* mrow = (const uint32_t*)M + ((size_t)(bh * S_ + q0 + row)) * S_ + wq0 * 32;
#pragma unroll
      for (int j = 0; j < 16; ++j) {
        uint32_t bits = 0;
#pragma unroll
        for (int u = 0; u < 8; ++u) {
          uint4v wv = *(const uint4v*)(mrow + j * 32 + u * 4);
          uint32_t nzb = (wv.x ? 1u : 0u) | (wv.y ? 2u : 0u) | (wv.z ? 4u : 0u) | (wv.w ? 8u : 0u);
          bits |= nzb << (u * 4);
        }
        mbits[row * 65 + wq0 + j] = bits;
      }
    }
  }

  // ---- Q as B-frag: lane holds Q[qrow][.] ----
  short8 qB[2];
  {
    const float* qr = Q + ((size_t)(bh * S_ + qrow)) * D_;
    float4v x0 = *(const float4v*)(qr + g * 8);
    float4v x1 = *(const float4v*)(qr + g * 8 + 4);
    float4v y0 = *(const float4v*)(qr + 32 + g * 8);
    float4v y1 = *(const float4v*)(qr + 32 + g * 8 + 4);
    short8 f;
    f[0]=f2bf(x0.x); f[1]=f2bf(x0.y); f[2]=f2bf(x0.z); f[3]=f2bf(x0.w);
    f[4]=f2bf(x1.x); f[5]=f2bf(x1.y); f[6]=f2bf(x1.z); f[7]=f2bf(x1.w);
    qB[0] = f;
    f[0]=f2bf(y0.x); f[1]=f2bf(y0.y); f[2]=f2bf(y0.z); f[3]=f2bf(y0.w);
    f[4]=f2bf(y1.x); f[5]=f2bf(y1.y); f[6]=f2bf(y1.z); f[7]=f2bf(y1.w);
    qB[1] = f;
  }

  // ---- staging: waves 0-3 relay K (XOR-swizzled), waves 4-7 relay V ----
  const bool kstager = (widx < 4);
  const bool vstager = (widx >= 4) && (PREP != 0);
  const int  sr = (widx << 3) + (lane >> 3);
  const int  sp = lane & 7;
  const int  sdst = sr * 64 + ((sp ^ (sr & 7)) << 3);
  const int  vr = ((widx - 4) << 4) + (lane >> 2);
  const int  vp = lane & 3;
  short8  kreg, vreg;
  float4v kf0, kf1;
#define ISSUE(W) do {                                                          \
    if (kstager) {                                                             \
      if (PREP) kreg = *(const short8*)(Kbp + (size_t)((W) * 32 + sr) * 64 + sp * 8); \
      else { const float* s_ = Kfp + (size_t)((W) * 32 + sr) * 64 + sp * 8;    \
             kf0 = *(const float4v*)s_; kf1 = *(const float4v*)(s_ + 4); }     \
    } else if (vstager) {                                                      \
      vreg = *(const short8*)(VTp + (size_t)vr * S_ + (W) * 32 + vp * 8);      \
    } } while (0)
#define WRITE(BUF) do {                                                        \
    if (kstager) {                                                             \
      short8 o_;                                                               \
      if (PREP) o_ = kreg;                                                     \
      else { o_[0]=f2bf(kf0.x); o_[1]=f2bf(kf0.y); o_[2]=f2bf(kf0.z); o_[3]=f2bf(kf0.w); \
             o_[4]=f2bf(kf1.x); o_[5]=f2bf(kf1.y); o_[6]=f2bf(kf1.z); o_[7]=f2bf(kf1.w); } \
      *(short8*)&kbuf[BUF][sdst] = o_;                                         \
    } else if (vstager) {                                                      \
      *(short8*)&vbuf[BUF][vr * VBS + vp * 8] = vreg;                          \
    } } while (0)

  const int ka0 = ((g       ^ (c & 7)) << 3);
  const int ka1 = (((g + 4) ^ (c & 7)) << 3);
  const uint32_t* mrow = &mbits[(widx * 16 + c) * 65];

  ISSUE(0); WRITE(0); ISSUE(1);
  __syncthreads();

  // ---- bitmap dump: linear, full-line NT stores (one LDS row per wave-instr) ----
  if (BM) {
    uint32_t* mg = mbitsG + ((size_t)(bh * S_ + q0)) * 64;
#pragma unroll
    for (int i = 0; i < 16; ++i) {
      const int wdx = i * 512 + tid;            // 0..8191
      const int row = wdx >> 6, wir = wdx & 63;
      __builtin_nontemporal_store(mbits[row * 65 + wir], mg + wdx);
    }
  }

  float rsv = 0.0f;
  float4v cacc[4];
#pragma unroll
  for (int nd = 0; nd < 4; ++nd) cacc[nd] = (float4v){0.f, 0.f, 0.f, 0.f};
  short* eb = &ebounce[widx][0];

#pragma unroll 1
  for (int w = 0; w < NWIN; ++w) {
    const int cur = w & 1;
    const int kwin = w * 32;

    short8 vA0, vA1, vA2, vA3;
    if (PREP) {
      const short* vb = &vbuf[cur][0];
      vA0 = *(const short8*)(vb + (size_t)(c)      * VBS + g * 8);
      vA1 = *(const short8*)(vb + (size_t)(16 + c) * VBS + g * 8);
      vA2 = *(const short8*)(vb + (size_t)(32 + c) * VBS + g * 8);
      vA3 = *(const short8*)(vb + (size_t)(48 + c) * VBS + g * 8);
    } else {
      const float* vc = Vfp + (size_t)(kwin + g * 8) * D_ + c;
#pragma unroll
      for (int e = 0; e < 8; ++e) {
        vA0[e] = f2bf(vc[(size_t)e * D_]);
        vA1[e] = f2bf(vc[(size_t)e * D_ + 16]);
        vA2[e] = f2bf(vc[(size_t)e * D_ + 32]);
        vA3[e] = f2bf(vc[(size_t)e * D_ + 48]);
      }
    }

    const short* kb = &kbuf[cur][0];
    short8 a0 = *(const short8*)(kb + c * 64 + ka0);
    short8 a1 = *(const short8*)(kb + c * 64 + ka1);
    short8 a2 = *(const short8*)(kb + (c + 16) * 64 + ka0);
    short8 a3 = *(const short8*)(kb + (c + 16) * 64 + ka1);

    float4v acc0 = (float4v){0.f,0.f,0.f,0.f};
    float4v acc1 = (float4v){0.f,0.f,0.f,0.f};
    acc0 = __builtin_amdgcn_mfma_f32_16x16x32_bf16(a0, qB[0], acc0, 0, 0, 0);
    acc0 = __builtin_amdgcn_mfma_f32_16x16x32_bf16(a1, qB[1], acc0, 0, 0, 0);
    acc1 = __builtin_amdgcn_mfma_f32_16x16x32_bf16(a2, qB[0], acc1, 0, 0, 0);
    acc1 = __builtin_amdgcn_mfma_f32_16x16x32_bf16(a3, qB[1], acc1, 0, 0, 0);

    const uint32_t mw = mrow[w];
    float e0[4], e1[4];
#pragma unroll
    for (int r = 0; r < 4; ++r) {
      e0[r] = ((mw >> (4 * g + r)) & 1u)      ? 1.0f : __expf(acc0[r] * scale);
      e1[r] = ((mw >> (16 + 4 * g + r)) & 1u) ? 1.0f : __expf(acc1[r] * scale);
      rsv += e0[r] + e1[r];
    }
    uint2v lo, hi2;
    lo.x  = cvtpk(e0[0], e0[1]);  lo.y  = cvtpk(e0[2], e0[3]);
    hi2.x = cvtpk(e1[0], e1[1]);  hi2.y = cvtpk(e1[2], e1[3]);
    *(uint2v*)&eb[c * EBS + 4 * g]      = lo;
    *(uint2v*)&eb[c * EBS + 16 + 4 * g] = hi2;
    const short8 bfrag = *(const short8*)&eb[c * EBS + g * 8];

    cacc[0] = __builtin_amdgcn_mfma_f32_16x16x32_bf16(vA0, bfrag, cacc[0], 0, 0, 0);
    cacc[1] = __builtin_amdgcn_mfma_f32_16x16x32_bf16(vA1, bfrag, cacc[1], 0, 0, 0);
    cacc[2] = __builtin_amdgcn_mfma_f32_16x16x32_bf16(vA2, bfrag, cacc[2], 0, 0, 0);
    cacc[3] = __builtin_amdgcn_mfma_f32_16x16x32_bf16(vA3, bfrag, cacc[3], 0, 0, 0);

    if (w + 1 < NWIN) {
      WRITE(cur ^ 1);
      if (w + 2 < NWIN) ISSUE(w + 2);
      __syncthreads();
    }
  }
#undef ISSUE
#undef WRITE

  rsv += __shfl_xor(rsv, 16);
  rsv += __shfl_xor(rsv, 32);
  const float linv = 1.0f / rsv;
  if (g == 0) linvG[(size_t)bh * S_ + qrow] = linv;
  __syncthreads();                              // mask dead; alias mbits for ctx

  // ---- context epilogue: normalize cacc, LDS transpose (stride 66), store ----
  {
    float* cst = (float*)mbits;                 // [128][66] floats
#pragma unroll
    for (int nd = 0; nd < 4; ++nd) {
      float4v v;
#pragma unroll
      for (int r = 0; r < 4; ++r) v[r] = cacc[nd][r] * linv;
      *(float4v*)&cst[(widx * 16 + c) * 66 + nd * 16 + 4 * g] = v;
    }
    __syncthreads();
    const int qq = tid >> 2, ch = tid & 3;
    const float* src = &cst[qq * 66 + ch * 16];
    float* dst = outC + ((size_t)(bh * S_ + q0 + qq)) * D_ + ch * 16;
    float4v c0 = *(const float4v*)src;
    float4v c1 = *(const float4v*)(src + 4);
    float4v c2 = *(const float4v*)(src + 8);
    float4v c3 = *(const float4v*)(src + 12);
    __builtin_nontemporal_store(c0, (float4v*)dst);
    __builtin_nontemporal_store(c1, (float4v*)(dst + 4));
    __builtin_nontemporal_store(c2, (float4v*)(dst + 8));
    __builtin_nontemporal_store(c3, (float4v*)(dst + 12));
  }
}

// =============== Pass 2: QK -> exp -> xlinv -> full-line nt stores ===========
template <int PREP, int BM>
__global__ __launch_bounds__(256, 7) void k_store(
    const float* __restrict__ Q, const float* __restrict__ K,
    const float* __restrict__ scale_p, const uint8_t* __restrict__ M,
    const uint32_t* __restrict__ flag, const short* __restrict__ Kbf,
    const float* __restrict__ linvG, const uint32_t* __restrict__ mbitsG,
    float* __restrict__ outA)
{
  __shared__ uint32_t mbits2[64 * 68];          // stride 68 (16B-aligned rows)
  __shared__ short eb2[4][16 * EBS];

  const int bx  = (blockIdx.x & 7) * 256 + (blockIdx.x >> 3);
  const int bh  = bx >> 5;
  const int q0  = (bx & 31) * 64;

  const int tid  = threadIdx.x;
  const int wv   = tid >> 6;
  const int lane = tid & 63;
  const int g    = lane >> 4;
  const int c    = lane & 15;
  const int qrow = q0 + wv * 16 + c;

  const float scale = scale_p[0];
  const uint32_t fl = flag[0];

  const short* Kbp = Kbf + (size_t)bh * S_ * D_;
  const float* Kfp = K + (size_t)bh * S_ * D_;

  // ---- bitmap prologue: 64 rows (stride 68) ----
  if (BM) {
    const uint32_t* mg = mbitsG + ((size_t)(bh * S_ + q0)) * 64;
#pragma unroll
    for (int i = 0; i < 4; ++i) {
      const int idx4 = i * 256 + tid;
      uint4v v = *(const uint4v*)(mg + (size_t)idx4 * 4);
      const int w0 = idx4 * 4, row = w0 >> 6, wir = w0 & 63;
      *(uint4v*)&mbits2[row * 68 + wir] = v;
    }
  } else {
    const int row = tid >> 2;
    const int wq0 = (tid & 3) * 16;
    if (fl == 3u) {
      const uint8_t* mrow = M + ((size_t)(bh * S_ + q0 + row)) * S_ + wq0 * 32;
#pragma unroll
      for (int j = 0; j < 16; ++j) {
        uint4v a = *(const uint4v*)(mrow + j * 32);
        uint4v b = *(const uint4v*)(mrow + j * 32 + 16);
        mbits2[row * 68 + wq0 + j] =
            nib(a.x) | (nib(a.y) << 4) | (nib(a.z) << 8)  | (nib(a.w) << 12)
          | (nib(b.x) << 16) | (nib(b.y) << 20) | (nib(b.z) << 24) | (nib(b.w) << 28);
      }
    } else {
      const uint32_t* mrow = (const uint32_t*)M + ((size_t)(bh * S_ + q0 + row)) * S_ + wq0 * 32;
#pragma unroll
      for (int j = 0; j < 16; ++j) {
        uint32_t bits = 0;
#pragma unroll
        for (int u = 0; u < 8; ++u) {
          uint4v wvv = *(const uint4v*)(mrow + j * 32 + u * 4);
          uint32_t nzb = (wvv.x ? 1u : 0u) | (wvv.y ? 2u : 0u) | (wvv.z ? 4u : 0u) | (wvv.w ? 8u : 0u);
          bits |= nzb << (u * 4);
        }
        mbits2[row * 68 + wq0 + j] = bits;
      }
    }
  }

  // ---- Q as B-frag + per-row inverse sum (register) ----
  short8 qB[2];
  {
    const float* qr = Q + ((size_t)(bh * S_ + qrow)) * D_;
    float4v x0 = *(const float4v*)(qr + g * 8);
    float4v x1 = *(const float4v*)(qr + g * 8 + 4);
    float4v y0 = *(const float4v*)(qr + 32 + g * 8);
    float4v y1 = *(const float4v*)(qr + 32 + g * 8 + 4);
    short8 f;
    f[0]=f2bf(x0.x); f[1]=f2bf(x0.y); f[2]=f2bf(x0.z); f[3]=f2bf(x0.w);
    f[4]=f2bf(x1.x); f[5]=f2bf(x1.y); f[6]=f2bf(x1.z); f[7]=f2bf(x1.w);
    qB[0] = f;
    f[0]=f2bf(y0.x); f[1]=f2bf(y0.y); f[2]=f2bf(y0.z); f[3]=f2bf(y0.w);
    f[4]=f2bf(y1.x); f[5]=f2bf(y1.y); f[6]=f2bf(y1.z); f[7]=f2bf(y1.w);
    qB[1] = f;
  }
  const float linvq = linvG[(size_t)bh * S_ + qrow];
  __syncthreads();

  const uint32_t* mrow = &mbits2[(wv * 16 + c) * 68];
  short* eb = &eb2[wv][0];
  const int srow = lane >> 3;
  const int scol = lane & 7;
  float* arow0 = outA + ((size_t)(bh * S_ + q0 + wv * 16 + srow)) * S_ + scol * 4;
  float* arow1 = outA + ((size_t)(bh * S_ + q0 + wv * 16 + srow + 8)) * S_ + scol * 4;

#pragma unroll 1
  for (int w = 0; w < NWIN; ++w) {
    const int kwin = w * 32;

    float4v acc0 = (float4v){0.f,0.f,0.f,0.f};
    float4v acc1 = (float4v){0.f,0.f,0.f,0.f};
    if (PREP) {
      const short* kr = Kbp + (size_t)(kwin + c) * D_ + g * 8;
      short8 a0 = *(const short8*)kr;
      short8 a1 = *(const short8*)(kr + 32);
      const short* kr1 = kr + 16 * D_;
      short8 a2 = *(const short8*)kr1;
      short8 a3 = *(const short8*)(kr1 + 32);
      acc0 = __builtin_amdgcn_mfma_f32_16x16x32_bf16(a0, qB[0], acc0, 0, 0, 0);
      acc0 = __builtin_amdgcn_mfma_f32_16x16x32_bf16(a1, qB[1], acc0, 0, 0, 0);
      acc1 = __builtin_amdgcn_mfma_f32_16x16x32_bf16(a2, qB[0], acc1, 0, 0, 0);
      acc1 = __builtin_amdgcn_mfma_f32_16x16x32_bf16(a3, qB[1], acc1, 0, 0, 0);
    } else {
      const float* kr = Kfp + (size_t)(kwin + c) * D_ + g * 8;
      const float* kr1 = kr + 16 * D_;
      short8 a0, a1, a2, a3;
#pragma unroll
      for (int e = 0; e < 8; ++e) {
        a0[e] = f2bf(kr[e]);  a1[e] = f2bf(kr[32 + e]);
        a2[e] = f2bf(kr1[e]); a3[e] = f2bf(kr1[32 + e]);
      }
      acc0 = __builtin_amdgcn_mfma_f32_16x16x32_bf16(a0, qB[0], acc0, 0, 0, 0);
      acc0 = __builtin_amdgcn_mfma_f32_16x16x32_bf16(a1, qB[1], acc0, 0, 0, 0);
      acc1 = __builtin_amdgcn_mfma_f32_16x16x32_bf16(a2, qB[0], acc1, 0, 0, 0);
      acc1 = __builtin_amdgcn_mfma_f32_16x16x32_bf16(a3, qB[1], acc1, 0, 0, 0);
    }

    const uint32_t mw = mrow[w];
    float n0[4], n1[4];
#pragma unroll
    for (int r = 0; r < 4; ++r) {
      n0[r] = (((mw >> (4 * g + r)) & 1u)      ? 1.0f : __expf(acc0[r] * scale)) * linvq;
      n1[r] = (((mw >> (16 + 4 * g + r)) & 1u) ? 1.0f : __expf(acc1[r] * scale)) * linvq;
    }
    uint2v lo, hi2;
    lo.x  = cvtpk(n0[0], n0[1]);  lo.y  = cvtpk(n0[2], n0[3]);
    hi2.x = cvtpk(n1[0], n1[1]);  hi2.y = cvtpk(n1[2], n1[3]);
    *(uint2v*)&eb[c * EBS + 4 * g]      = lo;
    *(uint2v*)&eb[c * EBS + 16 + 4 * g] = hi2;

    const uint2v ev0 = *(const uint2v*)&eb[srow * EBS + scol * 4];
    const uint2v ev1 = *(const uint2v*)&eb[(srow + 8) * EBS + scol * 4];
    float4v s0, s1;
    s0.x = bf2f(ev0.x & 0xffff); s0.y = bf2f(ev0.x >> 16);
    s0.z = bf2f(ev0.y & 0xffff); s0.w = bf2f(ev0.y >> 16);
    s1.x = bf2f(ev1.x & 0xffff); s1.y = bf2f(ev1.x >> 16);
    s1.z = bf2f(ev1.y & 0xffff); s1.w = bf2f(ev1.y >> 16);
    __builtin_nontemporal_store(s0, (float4v*)(arow0 + kwin));
    __builtin_nontemporal_store(s1, (float4v*)(arow1 + kwin));
  }
}

extern "C" void kernel_launch(void* const* d_in, const int* in_sizes, int n_in,
                              void* d_out, int out_size, void* d_ws, size_t ws_size,
                              hipStream_t stream) {
  const float*   Q     = (const float*)d_in[0];
  const float*   K     = (const float*)d_in[1];
  const float*   V     = (const float*)d_in[2];
  const float*   scale = (const float*)d_in[3];
  const uint8_t* M     = (const uint8_t*)d_in[4];
  uint32_t* flag  = (uint32_t*)d_ws;
  float*    linvG = (float*)((char*)d_ws + LINV_OFF);
  short*    Kbf   = (short*)((char*)d_ws + KBF_OFF);
  short*    VT    = (short*)((char*)d_ws + VT_OFF);
  uint32_t* mbG   = (uint32_t*)((char*)d_ws + MB_OFF);
  float* outC = (float*)d_out;
  float* outA = outC + (size_t)B_ * H_ * S_ * D_;

  hipMemsetAsync(flag, 0, 4, stream);
  detect_mask_dtype<<<dim3(1), dim3(256), 0, stream>>>(M, flag);

  const bool prep = ws_size >= VT_OFF + VT_BYTES;
  const bool bm   = ws_size >= MB_OFF + MB_BYTES;
  const int grid1 = B_ * H_ * (S_ / 128);       // 1024
  const int grid2 = B_ * H_ * (S_ / 64);        // 2048

  if (prep) {
    prep_k<<<dim3((B_ * H_ * S_ * D_) / (256 * 8)), dim3(256), 0, stream>>>(K, Kbf);
    prep_vt<<<dim3(B_ * H_ * (S_ / 64)), dim3(256), 0, stream>>>(V, VT);
    if (bm) {
      k_sums<1, 1><<<dim3(grid1), dim3(512), 0, stream>>>(
          Q, K, V, scale, M, flag, Kbf, VT, linvG, mbG, outC);
      k_store<1, 1><<<dim3(grid2), dim3(256), 0, stream>>>(
          Q, K, scale, M, flag, Kbf, linvG, mbG, outA);
    } else {
      k_sums<1, 0><<<dim3(grid1), dim3(512), 0, stream>>>(
          Q, K, V, scale, M, flag, Kbf, VT, linvG, mbG, outC);
      k_store<1, 0><<<dim3(grid2), dim3(256), 0, stream>>>(
          Q, K, scale, M, flag, Kbf, linvG, mbG, outA);
    }
  } else {
    k_sums<0, 0><<<dim3(grid1), dim3(512), 0, stream>>>(
        Q, K, V, scale, M, flag, Kbf, VT, linvG, mbG, outC);
    k_store<0, 0><<<dim3(grid2), dim3(256), 0, stream>>>(
        Q, K, scale, M, flag, Kbf, linvG, mbG, outA);
  }
}